// Round 8
// baseline (419.848 us; speedup 1.0000x reference)
//
#include <hip/hip_runtime.h>
#include <hip/hip_fp16.h>

typedef unsigned long long ull;

// ---------------- CSR construction ----------------

__global__ void count_kernel(const int* __restrict__ dst, int* __restrict__ counts, int E) {
    int e = blockIdx.x * 256 + threadIdx.x;
    if (e < E) atomicAdd(&counts[dst[e]], 1);
}

__global__ void scan_local(const int* __restrict__ counts, int* __restrict__ rowptr,
                           int* __restrict__ bsums, float* __restrict__ dinv, int N) {
    __shared__ int sm[256];
    int t = threadIdx.x;
    int gid = blockIdx.x * 256 + t;
    int v = (gid < N) ? counts[gid] : 0;
    if (gid < N) dinv[gid] = rsqrtf((float)v + 1.0f);
    int x = v;
    sm[t] = x; __syncthreads();
    for (int off = 1; off < 256; off <<= 1) {
        int y = (t >= off) ? sm[t - off] : 0;
        __syncthreads();
        x += y; sm[t] = x; __syncthreads();
    }
    if (gid < N) rowptr[gid] = x - v;
    if (t == 255) bsums[blockIdx.x] = x;
}

__global__ void scan_bsums(int* bsums, int nb) {
    __shared__ int sm[512];
    int t = threadIdx.x;
    int v = (t < nb) ? bsums[t] : 0;
    int x = v;
    sm[t] = x; __syncthreads();
    for (int off = 1; off < 512; off <<= 1) {
        int y = (t >= off) ? sm[t - off] : 0;
        __syncthreads();
        x += y; sm[t] = x; __syncthreads();
    }
    if (t < nb) bsums[t] = x - v;
}

__global__ void scan_add(int* __restrict__ rowptr, const int* __restrict__ bsums, int N) {
    int gid = blockIdx.x * 256 + threadIdx.x;
    if (gid < N) rowptr[gid] += bsums[blockIdx.x];
}

// 4-byte edge record: just src. dinv[src] is folded into the gathered panel
// (rows pre-scaled), halving fill's scattered write-line traffic (R6: 101 MB
// WRITE_SIZE = 64B/line per 8B record).

__global__ void fill_kernel(const int* __restrict__ src, const int* __restrict__ dst,
                            const int* __restrict__ rowptr, int* __restrict__ fillc,
                            int* __restrict__ esrc, int E) {
    int e = blockIdx.x * 256 + threadIdx.x;
    if (e < E) {
        int d = dst[e];
        int pos = rowptr[d] + atomicAdd(&fillc[d], 1);
        esrc[pos] = src[e];
    }
}

// ---------------- xw = dinv * (X @ W1) -> fp16 (pre-scaled rows) ----------------

__global__ void __launch_bounds__(128)
gemm64_kernel(const float* __restrict__ X, const float* __restrict__ W,
              const float* __restrict__ dinv, __half* __restrict__ out, int N) {
    __shared__ float Wl[64 * 64];
    __shared__ float hbuf[2][256];
    int tid = threadIdx.x;
    int lane = tid & 63;
    for (int i = tid; i < 4096; i += 128) Wl[i] = W[i];
    __syncthreads();
    int wi = __builtin_amdgcn_readfirstlane(tid >> 6);
    float* hb = &hbuf[wi][0];
    int g0 = blockIdx.x * 2 + wi;
    int ng = gridDim.x * 2;
    int NG = (N + 3) >> 2;
    for (int g = g0; g < NG; g += ng) {
        int v0 = g * 4;
        float x0 = (v0 + 0 < N) ? X[(size_t)(v0 + 0) * 64 + lane] : 0.f;
        float x1 = (v0 + 1 < N) ? X[(size_t)(v0 + 1) * 64 + lane] : 0.f;
        float x2 = (v0 + 2 < N) ? X[(size_t)(v0 + 2) * 64 + lane] : 0.f;
        float x3 = (v0 + 3 < N) ? X[(size_t)(v0 + 3) * 64 + lane] : 0.f;
        float d0 = (v0 + 0 < N) ? dinv[v0 + 0] : 0.f;
        float d1 = (v0 + 1 < N) ? dinv[v0 + 1] : 0.f;
        float d2 = (v0 + 2 < N) ? dinv[v0 + 2] : 0.f;
        float d3 = (v0 + 3 < N) ? dinv[v0 + 3] : 0.f;
        *(float4*)&hb[lane * 4] = make_float4(x0, x1, x2, x3);
        float y0 = 0.f, y1 = 0.f, y2 = 0.f, y3 = 0.f;
#pragma unroll 8
        for (int k = 0; k < 64; ++k) {
            float4 hk = *(const float4*)&hb[k * 4];
            float w = Wl[k * 64 + lane];
            y0 = fmaf(hk.x, w, y0);
            y1 = fmaf(hk.y, w, y1);
            y2 = fmaf(hk.z, w, y2);
            y3 = fmaf(hk.w, w, y3);
        }
        if (v0 + 0 < N) out[(size_t)(v0 + 0) * 64 + lane] = __float2half(d0 * y0);
        if (v0 + 1 < N) out[(size_t)(v0 + 1) * 64 + lane] = __float2half(d1 * y1);
        if (v0 + 2 < N) out[(size_t)(v0 + 2) * 64 + lane] = __float2half(d2 * y2);
        if (v0 + 3 < N) out[(size_t)(v0 + 3) * 64 + lane] = __float2half(d3 * y3);
    }
}

// ---- fp16 helper: add 4 halves (8B) into fp32 accumulator ----

__device__ __forceinline__ void add4(float* a, uint2 raw) {
    float2 v0 = __half22float2(*(const __half2*)&raw.x);
    float2 v1 = __half22float2(*(const __half2*)&raw.y);
    a[0] += v0.x;
    a[1] += v0.y;
    a[2] += v1.x;
    a[3] += v1.y;
}

// ------- layer1: 4-node gather (pre-scaled rows, 4B edge recs) + LDS MM @W2 -------
// Pad lanes use sentinel row N (zeroed) since there is no per-edge multiplier
// anymore. Y rows are stored pre-scaled by dinv[v] for agg_head's gather.

__global__ void agg_mm_kernel(const __half* __restrict__ XW, const int* __restrict__ esrc,
                              const int* __restrict__ rowptr, const int* __restrict__ counts,
                              const float* __restrict__ dinv, const float* __restrict__ b1,
                              const float* __restrict__ W2, __half* __restrict__ Y, int N) {
    __shared__ float Wl[64 * 64];
    __shared__ float hb[4][256];
    int tid = threadIdx.x;
    for (int i = tid; i < 4096; i += 256) Wl[i] = W2[i];
    __syncthreads();
    int lane = tid & 63, wave = tid >> 6;
    int g = lane >> 4;
    int cb = (lane & 15) * 4;
    const __half* Xcb = XW + cb;
    float4 bb4 = *(const float4*)&b1[cb];
    float* hbw = &hb[wave][0];
    int NQ = (N + 3) >> 2;
    for (int q = blockIdx.x * 4 + wave; q < NQ; q += gridDim.x * 4) {
        int v0 = q * 4;
        bool okB = v0 + 1 < N, okC = v0 + 2 < N, okD = v0 + 3 < N;
        int vA = v0;
        int vB = okB ? v0 + 1 : v0;
        int vC = okC ? v0 + 2 : v0;
        int vD = okD ? v0 + 3 : v0;
        int stA = __builtin_amdgcn_readfirstlane(rowptr[vA]);
        int cnA = __builtin_amdgcn_readfirstlane(counts[vA]);
        int stB = __builtin_amdgcn_readfirstlane(rowptr[vB]);
        int cnB = okB ? __builtin_amdgcn_readfirstlane(counts[vB]) : 0;
        int stC = __builtin_amdgcn_readfirstlane(rowptr[vC]);
        int cnC = okC ? __builtin_amdgcn_readfirstlane(counts[vC]) : 0;
        int stD = __builtin_amdgcn_readfirstlane(rowptr[vD]);
        int cnD = okD ? __builtin_amdgcn_readfirstlane(counts[vD]) : 0;
        float dvA = dinv[vA];
        float dvB = okB ? dinv[vB] : 0.f;
        float dvC = okC ? dinv[vC] : 0.f;
        float dvD = okD ? dinv[vD] : 0.f;
        float aA[4] = {0.f,0.f,0.f,0.f}, aB[4] = {0.f,0.f,0.f,0.f};
        float aC[4] = {0.f,0.f,0.f,0.f}, aD[4] = {0.f,0.f,0.f,0.f};
        int cntM = max(max(cnA, cnB), max(cnC, cnD));
        for (int base = 0; base < cntM; base += 64) {
            int nA = min(64, cnA - base), nB = min(64, cnB - base);
            int nC = min(64, cnC - base), nD = min(64, cnD - base);
            int iA = N, iB = N, iC = N, iD = N;   // sentinel row N = zeros
            if (lane < nA) iA = __builtin_nontemporal_load(&esrc[stA + base + lane]);
            if (lane < nB) iB = __builtin_nontemporal_load(&esrc[stB + base + lane]);
            if (lane < nC) iC = __builtin_nontemporal_load(&esrc[stC + base + lane]);
            if (lane < nD) iD = __builtin_nontemporal_load(&esrc[stD + base + lane]);
            int nbM = min(64, cntM - base);
            int nt = (nbM + 3) >> 2;
            for (int t = 0; t < nt; ++t) {
                int l = 4 * t + g;
                int sA = __shfl(iA, l);
                int sB = __shfl(iB, l);
                int sC = __shfl(iC, l);
                int sD = __shfl(iD, l);
                uint2 rA = *(const uint2*)&Xcb[(size_t)sA * 64];
                uint2 rB = *(const uint2*)&Xcb[(size_t)sB * 64];
                uint2 rC = *(const uint2*)&Xcb[(size_t)sC * 64];
                uint2 rD = *(const uint2*)&Xcb[(size_t)sD * 64];
                add4(aA, rA);
                add4(aB, rB);
                add4(aC, rC);
                add4(aD, rD);
            }
        }
        // cross-group reduce
#pragma unroll
        for (int i = 0; i < 4; ++i) {
            aA[i] += __shfl_xor(aA[i], 16); aA[i] += __shfl_xor(aA[i], 32);
            aB[i] += __shfl_xor(aB[i], 16); aB[i] += __shfl_xor(aB[i], 32);
            aC[i] += __shfl_xor(aC[i], 16); aC[i] += __shfl_xor(aC[i], 32);
            aD[i] += __shfl_xor(aD[i], 16); aD[i] += __shfl_xor(aD[i], 32);
        }
        // self-loop: rows are pre-scaled, so xw16[v] IS dinv[v]*row
        uint2 srA = *(const uint2*)&Xcb[(size_t)vA * 64];
        uint2 srB = *(const uint2*)&Xcb[(size_t)vB * 64];
        uint2 srC = *(const uint2*)&Xcb[(size_t)vC * 64];
        uint2 srD = *(const uint2*)&Xcb[(size_t)vD * 64];
        add4(aA, srA); add4(aB, srB);
        add4(aC, srC); add4(aD, srD);
        float hA[4], hB[4], hC[4], hD[4];
        const float* bbp = (const float*)&bb4;
#pragma unroll
        for (int i = 0; i < 4; ++i) {
            hA[i] = fmaxf(fmaf(dvA, aA[i], bbp[i]), 0.f);
            hB[i] = fmaxf(fmaf(dvB, aB[i], bbp[i]), 0.f);
            hC[i] = fmaxf(fmaf(dvC, aC[i], bbp[i]), 0.f);
            hD[i] = fmaxf(fmaf(dvD, aD[i], bbp[i]), 0.f);
        }
        // stage transposed (group g writes chain g)
#pragma unroll
        for (int i = 0; i < 4; ++i) {
            float s = (g == 0) ? hA[i] : (g == 1) ? hB[i] : (g == 2) ? hC[i] : hD[i];
            hbw[(cb + i) * 4 + g] = s;
        }
        // y = h @ W2; store pre-scaled by dinv for layer-2 gather
        float y0 = 0.f, y1 = 0.f, y2 = 0.f, y3 = 0.f;
#pragma unroll 8
        for (int k = 0; k < 64; ++k) {
            float4 hk = *(const float4*)&hbw[k * 4];
            float w = Wl[k * 64 + lane];
            y0 = fmaf(hk.x, w, y0);
            y1 = fmaf(hk.y, w, y1);
            y2 = fmaf(hk.z, w, y2);
            y3 = fmaf(hk.w, w, y3);
        }
        Y[(size_t)(v0 + 0) * 64 + lane] = __float2half(dvA * y0);
        if (okB) Y[(size_t)(v0 + 1) * 64 + lane] = __float2half(dvB * y1);
        if (okC) Y[(size_t)(v0 + 2) * 64 + lane] = __float2half(dvC * y2);
        if (okD) Y[(size_t)(v0 + 3) * 64 + lane] = __float2half(dvD * y3);
    }
}

// ------- layer2: same gather + epilogue, then MLP head via LDS MMs -------

__global__ void agg_head_kernel(const __half* __restrict__ Yin, const int* __restrict__ esrc,
                                const int* __restrict__ rowptr, const int* __restrict__ counts,
                                const float* __restrict__ dinv, const float* __restrict__ b2,
                                const float* __restrict__ dW1, const float* __restrict__ db1,
                                const float* __restrict__ dW2, const float* __restrict__ db2,
                                float* __restrict__ out, int N) {
    __shared__ float D1[64 * 64];
    __shared__ float Wh[64 * 16];
    __shared__ float hb[4][256];
    int tid = threadIdx.x;
    for (int i = tid; i < 4096; i += 256) D1[i] = dW1[i];
    for (int i = tid; i < 1024; i += 256) Wh[i] = dW2[i];
    __syncthreads();
    int lane = tid & 63, wave = tid >> 6;
    int g = lane >> 4;
    int cb = (lane & 15) * 4;
    const __half* Ycb = Yin + cb;
    int c = lane & 15, nj = lane >> 4;
    float4 bb4 = *(const float4*)&b2[cb];
    float bb1 = db1[lane];
    float ob  = db2[c];
    float* hbw = &hb[wave][0];
    int NQ = (N + 3) >> 2;
    for (int q = blockIdx.x * 4 + wave; q < NQ; q += gridDim.x * 4) {
        int v0 = q * 4;
        bool okB = v0 + 1 < N, okC = v0 + 2 < N, okD = v0 + 3 < N;
        int vA = v0;
        int vB = okB ? v0 + 1 : v0;
        int vC = okC ? v0 + 2 : v0;
        int vD = okD ? v0 + 3 : v0;
        int stA = __builtin_amdgcn_readfirstlane(rowptr[vA]);
        int cnA = __builtin_amdgcn_readfirstlane(counts[vA]);
        int stB = __builtin_amdgcn_readfirstlane(rowptr[vB]);
        int cnB = okB ? __builtin_amdgcn_readfirstlane(counts[vB]) : 0;
        int stC = __builtin_amdgcn_readfirstlane(rowptr[vC]);
        int cnC = okC ? __builtin_amdgcn_readfirstlane(counts[vC]) : 0;
        int stD = __builtin_amdgcn_readfirstlane(rowptr[vD]);
        int cnD = okD ? __builtin_amdgcn_readfirstlane(counts[vD]) : 0;
        float dvA = dinv[vA];
        float dvB = okB ? dinv[vB] : 0.f;
        float dvC = okC ? dinv[vC] : 0.f;
        float dvD = okD ? dinv[vD] : 0.f;
        float aA[4] = {0.f,0.f,0.f,0.f}, aB[4] = {0.f,0.f,0.f,0.f};
        float aC[4] = {0.f,0.f,0.f,0.f}, aD[4] = {0.f,0.f,0.f,0.f};
        int cntM = max(max(cnA, cnB), max(cnC, cnD));
        for (int base = 0; base < cntM; base += 64) {
            int nA = min(64, cnA - base), nB = min(64, cnB - base);
            int nC = min(64, cnC - base), nD = min(64, cnD - base);
            int iA = N, iB = N, iC = N, iD = N;
            if (lane < nA) iA = __builtin_nontemporal_load(&esrc[stA + base + lane]);
            if (lane < nB) iB = __builtin_nontemporal_load(&esrc[stB + base + lane]);
            if (lane < nC) iC = __builtin_nontemporal_load(&esrc[stC + base + lane]);
            if (lane < nD) iD = __builtin_nontemporal_load(&esrc[stD + base + lane]);
            int nbM = min(64, cntM - base);
            int nt = (nbM + 3) >> 2;
            for (int t = 0; t < nt; ++t) {
                int l = 4 * t + g;
                int sA = __shfl(iA, l);
                int sB = __shfl(iB, l);
                int sC = __shfl(iC, l);
                int sD = __shfl(iD, l);
                uint2 rA = *(const uint2*)&Ycb[(size_t)sA * 64];
                uint2 rB = *(const uint2*)&Ycb[(size_t)sB * 64];
                uint2 rC = *(const uint2*)&Ycb[(size_t)sC * 64];
                uint2 rD = *(const uint2*)&Ycb[(size_t)sD * 64];
                add4(aA, rA);
                add4(aB, rB);
                add4(aC, rC);
                add4(aD, rD);
            }
        }
#pragma unroll
        for (int i = 0; i < 4; ++i) {
            aA[i] += __shfl_xor(aA[i], 16); aA[i] += __shfl_xor(aA[i], 32);
            aB[i] += __shfl_xor(aB[i], 16); aB[i] += __shfl_xor(aB[i], 32);
            aC[i] += __shfl_xor(aC[i], 16); aC[i] += __shfl_xor(aC[i], 32);
            aD[i] += __shfl_xor(aD[i], 16); aD[i] += __shfl_xor(aD[i], 32);
        }
        uint2 srA = *(const uint2*)&Ycb[(size_t)vA * 64];
        uint2 srB = *(const uint2*)&Ycb[(size_t)vB * 64];
        uint2 srC = *(const uint2*)&Ycb[(size_t)vC * 64];
        uint2 srD = *(const uint2*)&Ycb[(size_t)vD * 64];
        add4(aA, srA); add4(aB, srB);
        add4(aC, srC); add4(aD, srD);
        float hA[4], hB[4], hC[4], hD[4];
        const float* bbp = (const float*)&bb4;
#pragma unroll
        for (int i = 0; i < 4; ++i) {
            hA[i] = fmaxf(fmaf(dvA, aA[i], bbp[i]), 0.f);
            hB[i] = fmaxf(fmaf(dvB, aB[i], bbp[i]), 0.f);
            hC[i] = fmaxf(fmaf(dvC, aC[i], bbp[i]), 0.f);
            hD[i] = fmaxf(fmaf(dvD, aD[i], bbp[i]), 0.f);
        }
#pragma unroll
        for (int i = 0; i < 4; ++i) {
            float s = (g == 0) ? hA[i] : (g == 1) ? hB[i] : (g == 2) ? hC[i] : hD[i];
            hbw[(cb + i) * 4 + g] = s;
        }
        // a = relu(h2 @ dW1 + db1)
        float y0 = bb1, y1 = bb1, y2 = bb1, y3 = bb1;
#pragma unroll 8
        for (int k = 0; k < 64; ++k) {
            float4 hk = *(const float4*)&hbw[k * 4];
            float w = D1[k * 64 + lane];
            y0 = fmaf(hk.x, w, y0);
            y1 = fmaf(hk.y, w, y1);
            y2 = fmaf(hk.z, w, y2);
            y3 = fmaf(hk.w, w, y3);
        }
        y0 = fmaxf(y0, 0.f); y1 = fmaxf(y1, 0.f);
        y2 = fmaxf(y2, 0.f); y3 = fmaxf(y3, 0.f);
        // drain LDS reads before overwriting hbw (same wave)
        asm volatile("s_waitcnt lgkmcnt(0)" ::: "memory");
        hbw[lane * 4 + 0] = y0;
        hbw[lane * 4 + 1] = y1;
        hbw[lane * 4 + 2] = y2;
        hbw[lane * 4 + 3] = y3;
        // out = a @ dW2 + db2 : lane -> (node nj, col c)
        float o = 0.f;
#pragma unroll 8
        for (int k = 0; k < 64; ++k) {
            o = fmaf(hbw[k * 4 + nj], Wh[k * 16 + c], o);
        }
        if (v0 + nj < N) out[(size_t)(v0 + nj) * 16 + c] = o + ob;
    }
}

// ---------------- launch ----------------

extern "C" void kernel_launch(void* const* d_in, const int* in_sizes, int n_in,
                              void* d_out, int out_size, void* d_ws, size_t ws_size,
                              hipStream_t stream) {
    const float* x   = (const float*)d_in[0];
    const int*   ei  = (const int*)d_in[1];
    const float* W1  = (const float*)d_in[2];
    const float* b1  = (const float*)d_in[3];
    const float* W2  = (const float*)d_in[4];
    const float* b2  = (const float*)d_in[5];
    const float* dW1 = (const float*)d_in[6];
    const float* db1 = (const float*)d_in[7];
    const float* dW2 = (const float*)d_in[8];
    const float* db2 = (const float*)d_in[9];
    float* out = (float*)d_out;

    int N = in_sizes[0] / 64;
    int E = in_sizes[1] / 2;
    const int* src = ei;
    const int* dst = ei + E;

    size_t off = 0;
    auto alloc = [&](size_t bytes) {
        void* p = (char*)d_ws + off;
        off += (bytes + 511) & ~(size_t)511;
        return p;
    };
    int Npad = (N + 127) & ~127;
    int*    counts = (int*)alloc((size_t)Npad * 8);     // [counts | fillc]
    int*    fillc  = counts + Npad;
    int*    rowptr = (int*)alloc((size_t)N * 4);
    int*    bsums  = (int*)alloc(512 * 4);
    int*    esrc   = (int*)alloc((size_t)E * 4);
    float*  dinv   = (float*)alloc((size_t)N * 4);
    __half* xw16   = (__half*)alloc((size_t)(N + 1) * 64 * 2);  // +1 sentinel row
    __half* yw16   = (__half*)alloc((size_t)(N + 1) * 64 * 2);

    hipMemsetAsync(counts, 0, (size_t)Npad * 8, stream);
    hipMemsetAsync(xw16 + (size_t)N * 64, 0, 128, stream);      // zero sentinel rows
    hipMemsetAsync(yw16 + (size_t)N * 64, 0, 128, stream);

    int nbN = (N + 255) / 256;
    int nbE = (E + 255) / 256;

    count_kernel<<<nbE, 256, 0, stream>>>(dst, counts, E);
    scan_local<<<nbN, 256, 0, stream>>>(counts, rowptr, bsums, dinv, N);
    scan_bsums<<<1, 512, 0, stream>>>(bsums, nbN);
    scan_add<<<nbN, 256, 0, stream>>>(rowptr, bsums, N);
    fill_kernel<<<nbE, 256, 0, stream>>>(src, dst, rowptr, fillc, esrc, E);

    gemm64_kernel<<<4096, 128, 0, stream>>>(x, W1, dinv, xw16, N);
    agg_mm_kernel<<<2048, 256, 0, stream>>>(xw16, esrc, rowptr, counts,
                                            dinv, b1, W2, yw16, N);
    agg_head_kernel<<<2048, 256, 0, stream>>>(yw16, esrc, rowptr, counts,
                                              dinv, b2, dW1, db1, dW2, db2, out, N);
}

// Round 9
// 392.235 us; speedup vs baseline: 1.0704x; 1.0704x over previous
//
#include <hip/hip_runtime.h>
#include <hip/hip_fp16.h>

typedef unsigned long long ull;

// ---------------- CSR construction ----------------

__global__ void count_kernel(const int* __restrict__ dst, int* __restrict__ counts, int E) {
    int e = blockIdx.x * 256 + threadIdx.x;
    if (e < E) atomicAdd(&counts[dst[e]], 1);
}

__global__ void scan_local(const int* __restrict__ counts, int* __restrict__ rowptr,
                           int* __restrict__ bsums, float* __restrict__ dinv, int N) {
    __shared__ int sm[256];
    int t = threadIdx.x;
    int gid = blockIdx.x * 256 + t;
    int v = (gid < N) ? counts[gid] : 0;
    if (gid < N) dinv[gid] = rsqrtf((float)v + 1.0f);
    int x = v;
    sm[t] = x; __syncthreads();
    for (int off = 1; off < 256; off <<= 1) {
        int y = (t >= off) ? sm[t - off] : 0;
        __syncthreads();
        x += y; sm[t] = x; __syncthreads();
    }
    if (gid < N) rowptr[gid] = x - v;
    if (t == 255) bsums[blockIdx.x] = x;
}

__global__ void scan_bsums(int* bsums, int nb) {
    __shared__ int sm[512];
    int t = threadIdx.x;
    int v = (t < nb) ? bsums[t] : 0;
    int x = v;
    sm[t] = x; __syncthreads();
    for (int off = 1; off < 512; off <<= 1) {
        int y = (t >= off) ? sm[t - off] : 0;
        __syncthreads();
        x += y; sm[t] = x; __syncthreads();
    }
    if (t < nb) bsums[t] = x - v;
}

__global__ void scan_add(int* __restrict__ rowptr, const int* __restrict__ bsums, int N) {
    int gid = blockIdx.x * 256 + threadIdx.x;
    if (gid < N) rowptr[gid] += bsums[blockIdx.x];
}

// XCD-region-partitioned fill: blockIdx = chunk*8 + p. Block (c,p) streams edge
// chunk c (non-temporal) and places only edges with dst in range p (N/8 nodes,
// esrc region ~800 KB). With round-robin dispatch, all blocks of a given p run
// on ONE XCD: region-p lines stay resident in that L2 and merge ~16 stores per
// 64B line before writeback (R8 measured per-store 64B writebacks, 107 MB).
// Correctness does not depend on the XCD mapping (G16) - only merging does.

__global__ void fill_kernel(const int* __restrict__ src, const int* __restrict__ dst,
                            const int* __restrict__ rowptr, int* __restrict__ fillc,
                            int* __restrict__ esrc, int E, int N, int CS) {
    int p = blockIdx.x & 7;
    int c = blockIdx.x >> 3;
    int lo = (int)(((long long)N * p) >> 3);
    int hi = (int)(((long long)N * (p + 1)) >> 3);
    int eend = min((c + 1) * CS, E);
    for (int e = c * CS + threadIdx.x; e < eend; e += 256) {
        int d = __builtin_nontemporal_load(&dst[e]);
        if (d >= lo && d < hi) {
            int s = __builtin_nontemporal_load(&src[e]);
            int pos = rowptr[d] + atomicAdd(&fillc[d], 1);
            esrc[pos] = s;
        }
    }
}

// ---------------- xw = dinv * (X @ W1) -> fp16 (pre-scaled rows) ----------------

__global__ void __launch_bounds__(128)
gemm64_kernel(const float* __restrict__ X, const float* __restrict__ W,
              const float* __restrict__ dinv, __half* __restrict__ out, int N) {
    __shared__ float Wl[64 * 64];
    __shared__ float hbuf[2][256];
    int tid = threadIdx.x;
    int lane = tid & 63;
    for (int i = tid; i < 4096; i += 128) Wl[i] = W[i];
    __syncthreads();
    int wi = __builtin_amdgcn_readfirstlane(tid >> 6);
    float* hb = &hbuf[wi][0];
    int g0 = blockIdx.x * 2 + wi;
    int ng = gridDim.x * 2;
    int NG = (N + 3) >> 2;
    for (int g = g0; g < NG; g += ng) {
        int v0 = g * 4;
        float x0 = (v0 + 0 < N) ? X[(size_t)(v0 + 0) * 64 + lane] : 0.f;
        float x1 = (v0 + 1 < N) ? X[(size_t)(v0 + 1) * 64 + lane] : 0.f;
        float x2 = (v0 + 2 < N) ? X[(size_t)(v0 + 2) * 64 + lane] : 0.f;
        float x3 = (v0 + 3 < N) ? X[(size_t)(v0 + 3) * 64 + lane] : 0.f;
        float d0 = (v0 + 0 < N) ? dinv[v0 + 0] : 0.f;
        float d1 = (v0 + 1 < N) ? dinv[v0 + 1] : 0.f;
        float d2 = (v0 + 2 < N) ? dinv[v0 + 2] : 0.f;
        float d3 = (v0 + 3 < N) ? dinv[v0 + 3] : 0.f;
        *(float4*)&hb[lane * 4] = make_float4(x0, x1, x2, x3);
        float y0 = 0.f, y1 = 0.f, y2 = 0.f, y3 = 0.f;
#pragma unroll 8
        for (int k = 0; k < 64; ++k) {
            float4 hk = *(const float4*)&hb[k * 4];
            float w = Wl[k * 64 + lane];
            y0 = fmaf(hk.x, w, y0);
            y1 = fmaf(hk.y, w, y1);
            y2 = fmaf(hk.z, w, y2);
            y3 = fmaf(hk.w, w, y3);
        }
        if (v0 + 0 < N) out[(size_t)(v0 + 0) * 64 + lane] = __float2half(d0 * y0);
        if (v0 + 1 < N) out[(size_t)(v0 + 1) * 64 + lane] = __float2half(d1 * y1);
        if (v0 + 2 < N) out[(size_t)(v0 + 2) * 64 + lane] = __float2half(d2 * y2);
        if (v0 + 3 < N) out[(size_t)(v0 + 3) * 64 + lane] = __float2half(d3 * y3);
    }
}

// ---- fp16 helper: add 4 halves (8B) into fp32 accumulator ----

__device__ __forceinline__ void add4(float* a, uint2 raw) {
    float2 v0 = __half22float2(*(const __half2*)&raw.x);
    float2 v1 = __half22float2(*(const __half2*)&raw.y);
    a[0] += v0.x;
    a[1] += v0.y;
    a[2] += v1.x;
    a[3] += v1.y;
}

// ------- layer1: 4-node gather (pre-scaled rows, 4B edge recs) + LDS MM @W2 -------

__global__ void agg_mm_kernel(const __half* __restrict__ XW, const int* __restrict__ esrc,
                              const int* __restrict__ rowptr, const int* __restrict__ counts,
                              const float* __restrict__ dinv, const float* __restrict__ b1,
                              const float* __restrict__ W2, __half* __restrict__ Y, int N) {
    __shared__ float Wl[64 * 64];
    __shared__ float hb[4][256];
    int tid = threadIdx.x;
    for (int i = tid; i < 4096; i += 256) Wl[i] = W2[i];
    __syncthreads();
    int lane = tid & 63, wave = tid >> 6;
    int g = lane >> 4;
    int cb = (lane & 15) * 4;
    const __half* Xcb = XW + cb;
    float4 bb4 = *(const float4*)&b1[cb];
    float* hbw = &hb[wave][0];
    int NQ = (N + 3) >> 2;
    for (int q = blockIdx.x * 4 + wave; q < NQ; q += gridDim.x * 4) {
        int v0 = q * 4;
        bool okB = v0 + 1 < N, okC = v0 + 2 < N, okD = v0 + 3 < N;
        int vA = v0;
        int vB = okB ? v0 + 1 : v0;
        int vC = okC ? v0 + 2 : v0;
        int vD = okD ? v0 + 3 : v0;
        int stA = __builtin_amdgcn_readfirstlane(rowptr[vA]);
        int cnA = __builtin_amdgcn_readfirstlane(counts[vA]);
        int stB = __builtin_amdgcn_readfirstlane(rowptr[vB]);
        int cnB = okB ? __builtin_amdgcn_readfirstlane(counts[vB]) : 0;
        int stC = __builtin_amdgcn_readfirstlane(rowptr[vC]);
        int cnC = okC ? __builtin_amdgcn_readfirstlane(counts[vC]) : 0;
        int stD = __builtin_amdgcn_readfirstlane(rowptr[vD]);
        int cnD = okD ? __builtin_amdgcn_readfirstlane(counts[vD]) : 0;
        float dvA = dinv[vA];
        float dvB = okB ? dinv[vB] : 0.f;
        float dvC = okC ? dinv[vC] : 0.f;
        float dvD = okD ? dinv[vD] : 0.f;
        float aA[4] = {0.f,0.f,0.f,0.f}, aB[4] = {0.f,0.f,0.f,0.f};
        float aC[4] = {0.f,0.f,0.f,0.f}, aD[4] = {0.f,0.f,0.f,0.f};
        int cntM = max(max(cnA, cnB), max(cnC, cnD));
        for (int base = 0; base < cntM; base += 64) {
            int nA = min(64, cnA - base), nB = min(64, cnB - base);
            int nC = min(64, cnC - base), nD = min(64, cnD - base);
            int iA = N, iB = N, iC = N, iD = N;   // sentinel row N = zeros
            if (lane < nA) iA = __builtin_nontemporal_load(&esrc[stA + base + lane]);
            if (lane < nB) iB = __builtin_nontemporal_load(&esrc[stB + base + lane]);
            if (lane < nC) iC = __builtin_nontemporal_load(&esrc[stC + base + lane]);
            if (lane < nD) iD = __builtin_nontemporal_load(&esrc[stD + base + lane]);
            int nbM = min(64, cntM - base);
            int nt = (nbM + 3) >> 2;
            for (int t = 0; t < nt; ++t) {
                int l = 4 * t + g;
                int sA = __shfl(iA, l);
                int sB = __shfl(iB, l);
                int sC = __shfl(iC, l);
                int sD = __shfl(iD, l);
                uint2 rA = *(const uint2*)&Xcb[(size_t)sA * 64];
                uint2 rB = *(const uint2*)&Xcb[(size_t)sB * 64];
                uint2 rC = *(const uint2*)&Xcb[(size_t)sC * 64];
                uint2 rD = *(const uint2*)&Xcb[(size_t)sD * 64];
                add4(aA, rA);
                add4(aB, rB);
                add4(aC, rC);
                add4(aD, rD);
            }
        }
        // cross-group reduce
#pragma unroll
        for (int i = 0; i < 4; ++i) {
            aA[i] += __shfl_xor(aA[i], 16); aA[i] += __shfl_xor(aA[i], 32);
            aB[i] += __shfl_xor(aB[i], 16); aB[i] += __shfl_xor(aB[i], 32);
            aC[i] += __shfl_xor(aC[i], 16); aC[i] += __shfl_xor(aC[i], 32);
            aD[i] += __shfl_xor(aD[i], 16); aD[i] += __shfl_xor(aD[i], 32);
        }
        // self-loop: rows are pre-scaled, so xw16[v] IS dinv[v]*row
        uint2 srA = *(const uint2*)&Xcb[(size_t)vA * 64];
        uint2 srB = *(const uint2*)&Xcb[(size_t)vB * 64];
        uint2 srC = *(const uint2*)&Xcb[(size_t)vC * 64];
        uint2 srD = *(const uint2*)&Xcb[(size_t)vD * 64];
        add4(aA, srA); add4(aB, srB);
        add4(aC, srC); add4(aD, srD);
        float hA[4], hB[4], hC[4], hD[4];
        const float* bbp = (const float*)&bb4;
#pragma unroll
        for (int i = 0; i < 4; ++i) {
            hA[i] = fmaxf(fmaf(dvA, aA[i], bbp[i]), 0.f);
            hB[i] = fmaxf(fmaf(dvB, aB[i], bbp[i]), 0.f);
            hC[i] = fmaxf(fmaf(dvC, aC[i], bbp[i]), 0.f);
            hD[i] = fmaxf(fmaf(dvD, aD[i], bbp[i]), 0.f);
        }
        // stage transposed (group g writes chain g)
#pragma unroll
        for (int i = 0; i < 4; ++i) {
            float s = (g == 0) ? hA[i] : (g == 1) ? hB[i] : (g == 2) ? hC[i] : hD[i];
            hbw[(cb + i) * 4 + g] = s;
        }
        // y = h @ W2; store pre-scaled by dinv for layer-2 gather
        float y0 = 0.f, y1 = 0.f, y2 = 0.f, y3 = 0.f;
#pragma unroll 8
        for (int k = 0; k < 64; ++k) {
            float4 hk = *(const float4*)&hbw[k * 4];
            float w = Wl[k * 64 + lane];
            y0 = fmaf(hk.x, w, y0);
            y1 = fmaf(hk.y, w, y1);
            y2 = fmaf(hk.z, w, y2);
            y3 = fmaf(hk.w, w, y3);
        }
        Y[(size_t)(v0 + 0) * 64 + lane] = __float2half(dvA * y0);
        if (okB) Y[(size_t)(v0 + 1) * 64 + lane] = __float2half(dvB * y1);
        if (okC) Y[(size_t)(v0 + 2) * 64 + lane] = __float2half(dvC * y2);
        if (okD) Y[(size_t)(v0 + 3) * 64 + lane] = __float2half(dvD * y3);
    }
}

// ------- layer2: same gather + epilogue, then MLP head via LDS MMs -------

__global__ void agg_head_kernel(const __half* __restrict__ Yin, const int* __restrict__ esrc,
                                const int* __restrict__ rowptr, const int* __restrict__ counts,
                                const float* __restrict__ dinv, const float* __restrict__ b2,
                                const float* __restrict__ dW1, const float* __restrict__ db1,
                                const float* __restrict__ dW2, const float* __restrict__ db2,
                                float* __restrict__ out, int N) {
    __shared__ float D1[64 * 64];
    __shared__ float Wh[64 * 16];
    __shared__ float hb[4][256];
    int tid = threadIdx.x;
    for (int i = tid; i < 4096; i += 256) D1[i] = dW1[i];
    for (int i = tid; i < 1024; i += 256) Wh[i] = dW2[i];
    __syncthreads();
    int lane = tid & 63, wave = tid >> 6;
    int g = lane >> 4;
    int cb = (lane & 15) * 4;
    const __half* Ycb = Yin + cb;
    int c = lane & 15, nj = lane >> 4;
    float4 bb4 = *(const float4*)&b2[cb];
    float bb1 = db1[lane];
    float ob  = db2[c];
    float* hbw = &hb[wave][0];
    int NQ = (N + 3) >> 2;
    for (int q = blockIdx.x * 4 + wave; q < NQ; q += gridDim.x * 4) {
        int v0 = q * 4;
        bool okB = v0 + 1 < N, okC = v0 + 2 < N, okD = v0 + 3 < N;
        int vA = v0;
        int vB = okB ? v0 + 1 : v0;
        int vC = okC ? v0 + 2 : v0;
        int vD = okD ? v0 + 3 : v0;
        int stA = __builtin_amdgcn_readfirstlane(rowptr[vA]);
        int cnA = __builtin_amdgcn_readfirstlane(counts[vA]);
        int stB = __builtin_amdgcn_readfirstlane(rowptr[vB]);
        int cnB = okB ? __builtin_amdgcn_readfirstlane(counts[vB]) : 0;
        int stC = __builtin_amdgcn_readfirstlane(rowptr[vC]);
        int cnC = okC ? __builtin_amdgcn_readfirstlane(counts[vC]) : 0;
        int stD = __builtin_amdgcn_readfirstlane(rowptr[vD]);
        int cnD = okD ? __builtin_amdgcn_readfirstlane(counts[vD]) : 0;
        float dvA = dinv[vA];
        float dvB = okB ? dinv[vB] : 0.f;
        float dvC = okC ? dinv[vC] : 0.f;
        float dvD = okD ? dinv[vD] : 0.f;
        float aA[4] = {0.f,0.f,0.f,0.f}, aB[4] = {0.f,0.f,0.f,0.f};
        float aC[4] = {0.f,0.f,0.f,0.f}, aD[4] = {0.f,0.f,0.f,0.f};
        int cntM = max(max(cnA, cnB), max(cnC, cnD));
        for (int base = 0; base < cntM; base += 64) {
            int nA = min(64, cnA - base), nB = min(64, cnB - base);
            int nC = min(64, cnC - base), nD = min(64, cnD - base);
            int iA = N, iB = N, iC = N, iD = N;
            if (lane < nA) iA = __builtin_nontemporal_load(&esrc[stA + base + lane]);
            if (lane < nB) iB = __builtin_nontemporal_load(&esrc[stB + base + lane]);
            if (lane < nC) iC = __builtin_nontemporal_load(&esrc[stC + base + lane]);
            if (lane < nD) iD = __builtin_nontemporal_load(&esrc[stD + base + lane]);
            int nbM = min(64, cntM - base);
            int nt = (nbM + 3) >> 2;
            for (int t = 0; t < nt; ++t) {
                int l = 4 * t + g;
                int sA = __shfl(iA, l);
                int sB = __shfl(iB, l);
                int sC = __shfl(iC, l);
                int sD = __shfl(iD, l);
                uint2 rA = *(const uint2*)&Ycb[(size_t)sA * 64];
                uint2 rB = *(const uint2*)&Ycb[(size_t)sB * 64];
                uint2 rC = *(const uint2*)&Ycb[(size_t)sC * 64];
                uint2 rD = *(const uint2*)&Ycb[(size_t)sD * 64];
                add4(aA, rA);
                add4(aB, rB);
                add4(aC, rC);
                add4(aD, rD);
            }
        }
#pragma unroll
        for (int i = 0; i < 4; ++i) {
            aA[i] += __shfl_xor(aA[i], 16); aA[i] += __shfl_xor(aA[i], 32);
            aB[i] += __shfl_xor(aB[i], 16); aB[i] += __shfl_xor(aB[i], 32);
            aC[i] += __shfl_xor(aC[i], 16); aC[i] += __shfl_xor(aC[i], 32);
            aD[i] += __shfl_xor(aD[i], 16); aD[i] += __shfl_xor(aD[i], 32);
        }
        uint2 srA = *(const uint2*)&Ycb[(size_t)vA * 64];
        uint2 srB = *(const uint2*)&Ycb[(size_t)vB * 64];
        uint2 srC = *(const uint2*)&Ycb[(size_t)vC * 64];
        uint2 srD = *(const uint2*)&Ycb[(size_t)vD * 64];
        add4(aA, srA); add4(aB, srB);
        add4(aC, srC); add4(aD, srD);
        float hA[4], hB[4], hC[4], hD[4];
        const float* bbp = (const float*)&bb4;
#pragma unroll
        for (int i = 0; i < 4; ++i) {
            hA[i] = fmaxf(fmaf(dvA, aA[i], bbp[i]), 0.f);
            hB[i] = fmaxf(fmaf(dvB, aB[i], bbp[i]), 0.f);
            hC[i] = fmaxf(fmaf(dvC, aC[i], bbp[i]), 0.f);
            hD[i] = fmaxf(fmaf(dvD, aD[i], bbp[i]), 0.f);
        }
#pragma unroll
        for (int i = 0; i < 4; ++i) {
            float s = (g == 0) ? hA[i] : (g == 1) ? hB[i] : (g == 2) ? hC[i] : hD[i];
            hbw[(cb + i) * 4 + g] = s;
        }
        // a = relu(h2 @ dW1 + db1)
        float y0 = bb1, y1 = bb1, y2 = bb1, y3 = bb1;
#pragma unroll 8
        for (int k = 0; k < 64; ++k) {
            float4 hk = *(const float4*)&hbw[k * 4];
            float w = D1[k * 64 + lane];
            y0 = fmaf(hk.x, w, y0);
            y1 = fmaf(hk.y, w, y1);
            y2 = fmaf(hk.z, w, y2);
            y3 = fmaf(hk.w, w, y3);
        }
        y0 = fmaxf(y0, 0.f); y1 = fmaxf(y1, 0.f);
        y2 = fmaxf(y2, 0.f); y3 = fmaxf(y3, 0.f);
        // drain LDS reads before overwriting hbw (same wave)
        asm volatile("s_waitcnt lgkmcnt(0)" ::: "memory");
        hbw[lane * 4 + 0] = y0;
        hbw[lane * 4 + 1] = y1;
        hbw[lane * 4 + 2] = y2;
        hbw[lane * 4 + 3] = y3;
        // out = a @ dW2 + db2 : lane -> (node nj, col c)
        float o = 0.f;
#pragma unroll 8
        for (int k = 0; k < 64; ++k) {
            o = fmaf(hbw[k * 4 + nj], Wh[k * 16 + c], o);
        }
        if (v0 + nj < N) out[(size_t)(v0 + nj) * 16 + c] = o + ob;
    }
}

// ---------------- launch ----------------

extern "C" void kernel_launch(void* const* d_in, const int* in_sizes, int n_in,
                              void* d_out, int out_size, void* d_ws, size_t ws_size,
                              hipStream_t stream) {
    const float* x   = (const float*)d_in[0];
    const int*   ei  = (const int*)d_in[1];
    const float* W1  = (const float*)d_in[2];
    const float* b1  = (const float*)d_in[3];
    const float* W2  = (const float*)d_in[4];
    const float* b2  = (const float*)d_in[5];
    const float* dW1 = (const float*)d_in[6];
    const float* db1 = (const float*)d_in[7];
    const float* dW2 = (const float*)d_in[8];
    const float* db2 = (const float*)d_in[9];
    float* out = (float*)d_out;

    int N = in_sizes[0] / 64;
    int E = in_sizes[1] / 2;
    const int* src = ei;
    const int* dst = ei + E;

    size_t off = 0;
    auto alloc = [&](size_t bytes) {
        void* p = (char*)d_ws + off;
        off += (bytes + 511) & ~(size_t)511;
        return p;
    };
    int Npad = (N + 127) & ~127;
    int*    counts = (int*)alloc((size_t)Npad * 8);     // [counts | fillc]
    int*    fillc  = counts + Npad;
    int*    rowptr = (int*)alloc((size_t)N * 4);
    int*    bsums  = (int*)alloc(512 * 4);
    int*    esrc   = (int*)alloc((size_t)E * 4);
    float*  dinv   = (float*)alloc((size_t)N * 4);
    __half* xw16   = (__half*)alloc((size_t)(N + 1) * 64 * 2);  // +1 sentinel row
    __half* yw16   = (__half*)alloc((size_t)(N + 1) * 64 * 2);

    hipMemsetAsync(counts, 0, (size_t)Npad * 8, stream);
    hipMemsetAsync(xw16 + (size_t)N * 64, 0, 128, stream);      // zero sentinel rows
    hipMemsetAsync(yw16 + (size_t)N * 64, 0, 128, stream);

    int nbN = (N + 255) / 256;
    int nbE = (E + 255) / 256;

    count_kernel<<<nbE, 256, 0, stream>>>(dst, counts, E);
    scan_local<<<nbN, 256, 0, stream>>>(counts, rowptr, bsums, dinv, N);
    scan_bsums<<<1, 512, 0, stream>>>(bsums, nbN);
    scan_add<<<nbN, 256, 0, stream>>>(rowptr, bsums, N);

    // XCD-region fill: 8 range-passes x nchunks chunks, one pass per XCD
    int nchunks = 800;
    int CS = (E + nchunks - 1) / nchunks;
    fill_kernel<<<nchunks * 8, 256, 0, stream>>>(src, dst, rowptr, fillc, esrc, E, N, CS);

    gemm64_kernel<<<4096, 128, 0, stream>>>(x, W1, dinv, xw16, N);
    agg_mm_kernel<<<2048, 256, 0, stream>>>(xw16, esrc, rowptr, counts,
                                            dinv, b1, W2, yw16, N);
    agg_head_kernel<<<2048, 256, 0, stream>>>(yw16, esrc, rowptr, counts,
                                              dinv, b2, dW1, db1, dW2, db2, out, N);
}